// Round 1
// baseline (1915.898 us; speedup 1.0000x reference)
//
#include <hip/hip_runtime.h>
#include <hip/hip_bf16.h>

// SwiGLU MLP: out = down( silu(x@Wg^T + bg) * (x@Wu^T + bu) ) @ ... + bd
// M=4096 tokens, H=4096, I=11008. fp32 in/out, bf16 MFMA compute.

#define M_TOK 4096
#define HID   4096
#define INT_  11008

typedef __attribute__((ext_vector_type(8))) short bf16x8;
typedef __attribute__((ext_vector_type(4))) float f32x4;

__device__ __forceinline__ unsigned short f2bf(float f) {
    union { float f; unsigned int u; } a; a.f = f;
    unsigned int u = a.u;
    u += 0x7fff + ((u >> 16) & 1);   // RNE
    return (unsigned short)(u >> 16);
}

__device__ __forceinline__ float bf2f(unsigned short h) {
    union { unsigned int u; float f; } a; a.u = ((unsigned int)h) << 16;
    return a.f;
}

// ---------------- fp32 -> bf16 convert (vectorized, grid-stride) ----------------
__global__ void cvt_f32_bf16(const float* __restrict__ in, unsigned short* __restrict__ out, int n4) {
    int stride = gridDim.x * blockDim.x;
    for (int i = blockIdx.x * blockDim.x + threadIdx.x; i < n4; i += stride) {
        float4 v = ((const float4*)in)[i];
        ushort4 o;
        o.x = f2bf(v.x); o.y = f2bf(v.y); o.z = f2bf(v.z); o.w = f2bf(v.w);
        ((ushort4*)out)[i] = o;
    }
}

// ---------------- 128x128-tile bf16 GEMM, C = A * B^T (+epilogue) ----------------
// A: M x K bf16 row-major; B: N x K bf16 row-major.
// EPI 0: store bf16 (acc + bias)                      -> gate pre-activation g
// EPI 1: store bf16 silu(g) * (acc + bias)            -> t (reads gbuf)
// EPI 2: store fp32 (acc + bias)                      -> final output
template<int EPI>
__global__ void gemm_bt(const unsigned short* __restrict__ A,
                        const unsigned short* __restrict__ B,
                        const float* __restrict__ bias,
                        const unsigned short* __restrict__ gbuf,
                        void* __restrict__ Cv,
                        int M, int N, int K) {
    __shared__ unsigned short As[128 * 32];
    __shared__ unsigned short Bs[128 * 32];

    const int tid  = threadIdx.x;
    const int lane = tid & 63;
    const int w    = tid >> 6;       // wave 0..3
    const int wm   = w >> 1, wn = w & 1;

    const int ntn = N >> 7;
    const int bm  = blockIdx.x / ntn;
    const int bn  = blockIdx.x % ntn;

    f32x4 acc[4][4];
#pragma unroll
    for (int m = 0; m < 4; ++m)
#pragma unroll
        for (int n = 0; n < 4; ++n)
            acc[m][n] = (f32x4){0.f, 0.f, 0.f, 0.f};

    // staging decomposition: elem e = i*2048 + w*512 + lane*8 ; r=e/32 c=e%32
    const int sr = (w << 4) + (lane >> 2);      // row within tile (+ i*64)
    const int sc = (lane & 3) << 3;             // col within 32
    const int sbase = (w << 9);                 // LDS elem base (+ i*2048), wave-uniform

    const unsigned short* Ag = A + (size_t)(bm * 128) * K;
    const unsigned short* Bg = B + (size_t)(bn * 128) * K;

    const int ar = lane & 15;                   // row/col within 16x16 frag
    const int kg = lane >> 4;                   // k-group 0..3 (8 elems each)
    const int aoff = (wm * 64 + ar) * 32 + kg * 8;   // + m*16*32
    const int boff = (wn * 64 + ar) * 32 + kg * 8;   // + n*16*32

    for (int k0 = 0; k0 < K; k0 += 32) {
        const unsigned short* a0 = Ag + (size_t)sr * K + k0 + sc;
        const unsigned short* b0 = Bg + (size_t)sr * K + k0 + sc;
#pragma unroll
        for (int i = 0; i < 2; ++i) {
            __builtin_amdgcn_global_load_lds(
                (__attribute__((address_space(1))) void*)(a0 + (size_t)i * 64 * K),
                (__attribute__((address_space(3))) void*)(As + sbase + i * 2048), 16, 0, 0);
            __builtin_amdgcn_global_load_lds(
                (__attribute__((address_space(1))) void*)(b0 + (size_t)i * 64 * K),
                (__attribute__((address_space(3))) void*)(Bs + sbase + i * 2048), 16, 0, 0);
        }
        __syncthreads();   // drains vmcnt+lgkmcnt before barrier

        bf16x8 af[4], bfr[4];
#pragma unroll
        for (int m = 0; m < 4; ++m) af[m]  = *(const bf16x8*)(As + aoff + m * 512);
#pragma unroll
        for (int n = 0; n < 4; ++n) bfr[n] = *(const bf16x8*)(Bs + boff + n * 512);
#pragma unroll
        for (int m = 0; m < 4; ++m)
#pragma unroll
            for (int n = 0; n < 4; ++n)
                acc[m][n] = __builtin_amdgcn_mfma_f32_16x16x32_bf16(af[m], bfr[n], acc[m][n], 0, 0, 0);
        __syncthreads();   // before next-tile overwrite of LDS
    }

    // epilogue — C/D layout: col = lane&15, row = (lane>>4)*4 + reg  [m89-verified]
    const int row0 = bm * 128 + wm * 64 + (lane >> 4) * 4;
    const int col0 = bn * 128 + wn * 64 + (lane & 15);
#pragma unroll
    for (int n = 0; n < 4; ++n) {
        const int col = col0 + n * 16;
        const float bv = bias[col];
#pragma unroll
        for (int m = 0; m < 4; ++m) {
            const int rb = row0 + m * 16;
#pragma unroll
            for (int j = 0; j < 4; ++j) {
                const size_t idx = (size_t)(rb + j) * (size_t)N + col;
                float v = acc[m][n][j] + bv;
                if (EPI == 0) {
                    ((unsigned short*)Cv)[idx] = f2bf(v);
                } else if (EPI == 1) {
                    float g = bf2f(gbuf[idx]);
                    float s = g / (1.f + __expf(-g));   // silu(g)
                    ((unsigned short*)Cv)[idx] = f2bf(s * v);
                } else {
                    ((float*)Cv)[idx] = v;
                }
            }
        }
    }
}

// ---------------- launcher ----------------
extern "C" void kernel_launch(void* const* d_in, const int* in_sizes, int n_in,
                              void* d_out, int out_size, void* d_ws, size_t ws_size,
                              hipStream_t stream) {
    const float* x  = (const float*)d_in[0];   // (2,2048,4096)
    const float* wg = (const float*)d_in[1];   // (11008,4096)
    const float* bg = (const float*)d_in[2];
    const float* wu = (const float*)d_in[3];
    const float* bu = (const float*)d_in[4];
    const float* wd = (const float*)d_in[5];   // (4096,11008)
    const float* bd = (const float*)d_in[6];

    const size_t NX = (size_t)M_TOK * HID;     // 16,777,216
    const size_t NW = (size_t)INT_ * HID;      // 45,088,768 (== M_TOK*INT_)

    unsigned short* ws = (unsigned short*)d_ws;
    unsigned short* Xb = ws;                   // x bf16
    unsigned short* S1 = Xb + NX;              // Wg -> later t
    unsigned short* S2 = S1 + NW;              // g  -> later Wd
    unsigned short* S3 = S2 + NW;              // Wu
    // peak ws need: (NX + 3*NW)*2 = 304,087,040 bytes

    dim3 blk(256);
    const int CG = 2048;

    cvt_f32_bf16<<<CG, blk, 0, stream>>>(x,  Xb, (int)(NX / 4));
    cvt_f32_bf16<<<CG, blk, 0, stream>>>(wg, S1, (int)(NW / 4));
    // gate: g = x @ Wg^T + bg  (bf16 -> S2)
    gemm_bt<0><<<dim3(32 * 86), blk, 0, stream>>>(Xb, S1, bg, (const unsigned short*)nullptr,
                                                  (void*)S2, M_TOK, INT_, HID);
    cvt_f32_bf16<<<CG, blk, 0, stream>>>(wu, S3, (int)(NW / 4));
    // up + fuse: t = silu(g) * (x @ Wu^T + bu)  (bf16 -> S1, Wg dead)
    gemm_bt<1><<<dim3(32 * 86), blk, 0, stream>>>(Xb, S3, bu, S2,
                                                  (void*)S1, M_TOK, INT_, HID);
    cvt_f32_bf16<<<CG, blk, 0, stream>>>(wd, S2, (int)(NW / 4));
    // down: out = t @ Wd^T + bd  (fp32 -> d_out)
    gemm_bt<2><<<dim3(32 * 32), blk, 0, stream>>>(S1, S2, bd, (const unsigned short*)nullptr,
                                                  d_out, M_TOK, HID, INT_);
}

// Round 2
// 1313.410 us; speedup vs baseline: 1.4587x; 1.4587x over previous
//
#include <hip/hip_runtime.h>
#include <hip/hip_bf16.h>

// SwiGLU MLP: out = down( silu(x@Wg^T + bg) * (x@Wu^T + bu) ) + bd
// M=4096 tokens, H=4096, I=11008. fp32 in/out, bf16 MFMA compute.
// GEMM: 256x256 tile, BK=32, 8 waves, 4-deep LDS pipeline, counted vmcnt(8),
// XOR-swizzled LDS (conflict-free ds_read_b128), XCD-aware block swizzle.

#define M_TOK 4096
#define HID   4096
#define INT_  11008

typedef __attribute__((ext_vector_type(8))) short bf16x8;
typedef __attribute__((ext_vector_type(4))) float f32x4;

__device__ __forceinline__ unsigned short f2bf(float f) {
    union { float f; unsigned int u; } a; a.f = f;
    unsigned int u = a.u;
    u += 0x7fff + ((u >> 16) & 1);   // RNE
    return (unsigned short)(u >> 16);
}

__device__ __forceinline__ float bf2f(unsigned short h) {
    union { unsigned int u; float f; } a; a.u = ((unsigned int)h) << 16;
    return a.f;
}

// ---------------- fp32 -> bf16 convert (vectorized, grid-stride) ----------------
__global__ void cvt_f32_bf16(const float* __restrict__ in, unsigned short* __restrict__ out, int n4) {
    int stride = gridDim.x * blockDim.x;
    for (int i = blockIdx.x * blockDim.x + threadIdx.x; i < n4; i += stride) {
        float4 v = ((const float4*)in)[i];
        ushort4 o;
        o.x = f2bf(v.x); o.y = f2bf(v.y); o.z = f2bf(v.z); o.w = f2bf(v.w);
        ((ushort4*)out)[i] = o;
    }
}

// ---------------- 256x256-tile bf16 GEMM, C = A * B^T (+epilogue) ----------------
// A: M x K bf16 row-major; B: N x K bf16 row-major. M%256==0, N%256==0, K%32==0,
// grid (M/256)*(N/256) divisible by 8.
// LDS: 4 K-tile buffers x (A 256x32 + B 256x32) bf16 = 128 KiB.
// Swizzle (involution, both sides): logical (row, slot s in 0..3 of 16B) stored at
// physical (row ^ ((row>>2)&1), s ^ (row&3)).
// EPI 0: store bf16 (acc+bias); EPI 1: store bf16 silu(g)*(acc+bias); EPI 2: fp32 (acc+bias)
template<int EPI>
__global__ __launch_bounds__(512, 2)
void gemm256(const unsigned short* __restrict__ A,
             const unsigned short* __restrict__ B,
             const float* __restrict__ bias,
             const unsigned short* __restrict__ gbuf,
             void* __restrict__ Cv,
             int M, int N, int K) {
    __shared__ unsigned short lds[4 * 16384];   // 128 KiB

    const int tid  = threadIdx.x;
    const int lane = tid & 63;
    const int w    = tid >> 6;       // wave 0..7
    const int wm   = w >> 2;         // 0..1  (M half)
    const int wn   = w & 3;          // 0..3  (N quarter)

    // XCD-aware bijective swizzle (grid % 8 == 0)
    const int ntn = N >> 8;
    const int chunk = gridDim.x >> 3;
    const int sw = (blockIdx.x & 7) * chunk + (blockIdx.x >> 3);
    const int bm = sw / ntn, bn = sw % ntn;

    // ---- staging source decode (inverse swizzle; LDS dest stays linear) ----
    // physical 16B slot lp = i*512 + tid covers (prow = lp>>2, ps = lp&3)
    size_t gOfs[2];
#pragma unroll
    for (int i = 0; i < 2; ++i) {
        int lp  = i * 512 + tid;
        int pr  = lp >> 2, ps = lp & 3;
        int row = pr ^ ((pr >> 2) & 1);      // logical row (involution)
        int s   = ps ^ (row & 3);            // logical 16B slot within row
        gOfs[i] = (size_t)row * K + s * 8;
    }
    const unsigned short* Ag = A + (size_t)(bm * 256) * K;
    const unsigned short* Bg = B + (size_t)(bn * 256) * K;

    // ---- ds_read fragment addresses (swizzled) ----
    const int ar  = lane & 15;               // row within 16x16 frag
    const int kg  = lane >> 4;               // k-group (8 elems)
    const int rsw = ar ^ ((ar >> 2) & 1);
    const int ssw = (kg ^ (ar & 3)) * 8;
    const int aoff = (wm * 128 + rsw) * 32 + ssw;          // + m*512
    const int boff = 8192 + (wn * 64 + rsw) * 32 + ssw;    // + n*512

    f32x4 acc[8][4];
#pragma unroll
    for (int m = 0; m < 8; ++m)
#pragma unroll
        for (int n = 0; n < 4; ++n)
            acc[m][n] = (f32x4){0.f, 0.f, 0.f, 0.f};

    const int NT = K >> 5;

    // ---- prologue: stage K-tiles 0,1,2 ----
#pragma unroll
    for (int tt = 0; tt < 3; ++tt) {
        unsigned short* dA = lds + tt * 16384 + w * 512;
        const unsigned short* sA = Ag + tt * 32;
        const unsigned short* sB = Bg + tt * 32;
#pragma unroll
        for (int i = 0; i < 2; ++i) {
            __builtin_amdgcn_global_load_lds(
                (__attribute__((address_space(1))) void*)(sA + gOfs[i]),
                (__attribute__((address_space(3))) void*)(dA + i * 4096), 16, 0, 0);
            __builtin_amdgcn_global_load_lds(
                (__attribute__((address_space(1))) void*)(sB + gOfs[i]),
                (__attribute__((address_space(3))) void*)(dA + 8192 + i * 4096), 16, 0, 0);
        }
    }
    asm volatile("s_waitcnt vmcnt(8)" ::: "memory");   // tile 0 landed (1,2 in flight)
    __builtin_amdgcn_s_barrier();

    // ---- main loop: per K-tile, 2 phases x 16 MFMA, counted vmcnt(8) ----
    for (int t = 0; t < NT; ++t) {
        const unsigned short* as = lds + (t & 3) * 16384;
        const int tb = (t + 3) & 3;
        const int ts = (t + 3 < NT) ? (t + 3) : (NT - 1);  // clamped re-stage: harmless
        const int k0s = ts * 32;
        unsigned short* dA = lds + tb * 16384 + w * 512;

        bf16x8 a_[4], b_[4];
        // ---- phase 1: frags m0-3 + all B; stage A of tile ts ----
#pragma unroll
        for (int m = 0; m < 4; ++m) a_[m] = *(const bf16x8*)(as + aoff + m * 512);
#pragma unroll
        for (int n = 0; n < 4; ++n) b_[n] = *(const bf16x8*)(as + boff + n * 512);
#pragma unroll
        for (int i = 0; i < 2; ++i)
            __builtin_amdgcn_global_load_lds(
                (__attribute__((address_space(1))) void*)(Ag + k0s + gOfs[i]),
                (__attribute__((address_space(3))) void*)(dA + i * 4096), 16, 0, 0);
        __builtin_amdgcn_s_barrier();
        asm volatile("s_waitcnt lgkmcnt(0)" ::: "memory");
        __builtin_amdgcn_s_setprio(1);
#pragma unroll
        for (int m = 0; m < 4; ++m)
#pragma unroll
            for (int n = 0; n < 4; ++n)
                acc[m][n] = __builtin_amdgcn_mfma_f32_16x16x32_bf16(a_[m], b_[n], acc[m][n], 0, 0, 0);
        __builtin_amdgcn_s_setprio(0);
        __builtin_amdgcn_s_barrier();

        // ---- phase 2: frags m4-7 (B reused); stage B of tile ts ----
#pragma unroll
        for (int m = 0; m < 4; ++m) a_[m] = *(const bf16x8*)(as + aoff + (4 + m) * 512);
#pragma unroll
        for (int i = 0; i < 2; ++i)
            __builtin_amdgcn_global_load_lds(
                (__attribute__((address_space(1))) void*)(Bg + k0s + gOfs[i]),
                (__attribute__((address_space(3))) void*)(dA + 8192 + i * 4096), 16, 0, 0);
        __builtin_amdgcn_s_barrier();
        asm volatile("s_waitcnt lgkmcnt(0)" ::: "memory");
        __builtin_amdgcn_s_setprio(1);
#pragma unroll
        for (int m = 0; m < 4; ++m)
#pragma unroll
            for (int n = 0; n < 4; ++n)
                acc[4 + m][n] = __builtin_amdgcn_mfma_f32_16x16x32_bf16(a_[m], b_[n], acc[4 + m][n], 0, 0, 0);
        __builtin_amdgcn_s_setprio(0);
        // counted wait: <=8 outstanding = tiles t+2,t+3; tile t+1 fully landed
        asm volatile("s_waitcnt vmcnt(8)" ::: "memory");
        __builtin_amdgcn_s_barrier();
    }

    // ---- epilogue: C/D layout col=lane&15, row=(lane>>4)*4+j  [m89-verified] ----
    const int row0 = bm * 256 + wm * 128 + (lane >> 4) * 4;
    const int col0 = bn * 256 + wn * 64 + (lane & 15);
#pragma unroll
    for (int n = 0; n < 4; ++n) {
        const int col = col0 + n * 16;
        const float bv = bias[col];
#pragma unroll
        for (int m = 0; m < 8; ++m) {
            const int rb = row0 + m * 16;
#pragma unroll
            for (int j = 0; j < 4; ++j) {
                const size_t idx = (size_t)(rb + j) * (size_t)N + col;
                float v = acc[m][n][j] + bv;
                if (EPI == 0) {
                    ((unsigned short*)Cv)[idx] = f2bf(v);
                } else if (EPI == 1) {
                    float g = bf2f(gbuf[idx]);
                    float s = g / (1.f + __expf(-g));   // silu(g)
                    ((unsigned short*)Cv)[idx] = f2bf(s * v);
                } else {
                    ((float*)Cv)[idx] = v;
                }
            }
        }
    }
}

// ---------------- launcher ----------------
extern "C" void kernel_launch(void* const* d_in, const int* in_sizes, int n_in,
                              void* d_out, int out_size, void* d_ws, size_t ws_size,
                              hipStream_t stream) {
    const float* x  = (const float*)d_in[0];   // (2,2048,4096)
    const float* wg = (const float*)d_in[1];   // (11008,4096)
    const float* bg = (const float*)d_in[2];
    const float* wu = (const float*)d_in[3];
    const float* bu = (const float*)d_in[4];
    const float* wd = (const float*)d_in[5];   // (4096,11008)
    const float* bd = (const float*)d_in[6];

    const size_t NX = (size_t)M_TOK * HID;     // 16,777,216
    const size_t NW = (size_t)INT_ * HID;      // 45,088,768 (== M_TOK*INT_)

    unsigned short* ws = (unsigned short*)d_ws;
    unsigned short* Xb = ws;                   // x bf16
    unsigned short* S1 = Xb + NX;              // Wg -> later t
    unsigned short* S2 = S1 + NW;              // g  -> later Wd
    unsigned short* S3 = S2 + NW;              // Wu
    // peak ws need: (NX + 3*NW)*2 = 304,087,040 bytes

    dim3 blk512(512);
    dim3 blk256(256);
    const int CG = 2048;

    cvt_f32_bf16<<<CG, blk256, 0, stream>>>(x,  Xb, (int)(NX / 4));
    cvt_f32_bf16<<<CG, blk256, 0, stream>>>(wg, S1, (int)(NW / 4));
    // gate: g = x @ Wg^T + bg  (bf16 -> S2)   grid 16*43=688 (688%8==0)
    gemm256<0><<<dim3(16 * 43), blk512, 0, stream>>>(Xb, S1, bg, (const unsigned short*)nullptr,
                                                     (void*)S2, M_TOK, INT_, HID);
    cvt_f32_bf16<<<CG, blk256, 0, stream>>>(wu, S3, (int)(NW / 4));
    // up + fuse: t = silu(g) * (x @ Wu^T + bu)  (bf16 -> S1, Wg dead)
    gemm256<1><<<dim3(16 * 43), blk512, 0, stream>>>(Xb, S3, bu, S2,
                                                     (void*)S1, M_TOK, INT_, HID);
    cvt_f32_bf16<<<CG, blk256, 0, stream>>>(wd, S2, (int)(NW / 4));
    // down: out = t @ Wd^T + bd  (fp32 -> d_out)  grid 16*16=256 (256%8==0)
    gemm256<2><<<dim3(16 * 16), blk512, 0, stream>>>(S1, S2, bd, (const unsigned short*)nullptr,
                                                     d_out, M_TOK, HID, INT_);
}

// Round 3
// 1232.634 us; speedup vs baseline: 1.5543x; 1.0655x over previous
//
#include <hip/hip_runtime.h>
#include <hip/hip_bf16.h>

// SwiGLU MLP: out = down( silu(x@Wg^T + bg) * (x@Wu^T + bu) ) + bd
// M=4096 tokens, H=4096, I=11008. fp32 in/out, bf16 MFMA compute.
// GEMM: 256x256 tile, BK=32, 8 waves, 4-deep LDS ring, counted vmcnt(8),
// 1 barrier/K-tile, register-double-buffered fragments (ds_read ahead of MFMA),
// XOR-swizzled LDS, XCD-aware bijective block swizzle.

#define M_TOK 4096
#define HID   4096
#define INT_  11008

typedef __attribute__((ext_vector_type(8))) short bf16x8;
typedef __attribute__((ext_vector_type(4))) float f32x4;

__device__ __forceinline__ unsigned short f2bf(float f) {
    union { float f; unsigned int u; } a; a.f = f;
    unsigned int u = a.u;
    u += 0x7fff + ((u >> 16) & 1);   // RNE
    return (unsigned short)(u >> 16);
}

__device__ __forceinline__ float bf2f(unsigned short h) {
    union { unsigned int u; float f; } a; a.u = ((unsigned int)h) << 16;
    return a.f;
}

// ---------------- fp32 -> bf16 convert (vectorized, grid-stride) ----------------
__global__ void cvt_f32_bf16(const float* __restrict__ in, unsigned short* __restrict__ out, int n4) {
    int stride = gridDim.x * blockDim.x;
    for (int i = blockIdx.x * blockDim.x + threadIdx.x; i < n4; i += stride) {
        float4 v = ((const float4*)in)[i];
        ushort4 o;
        o.x = f2bf(v.x); o.y = f2bf(v.y); o.z = f2bf(v.z); o.w = f2bf(v.w);
        ((ushort4*)out)[i] = o;
    }
}

#define GLL(gsrc, ldst) \
    __builtin_amdgcn_global_load_lds( \
        (__attribute__((address_space(1))) void*)(gsrc), \
        (__attribute__((address_space(3))) void*)(ldst), 16, 0, 0)

// ---------------- 256x256-tile bf16 GEMM, C = A * B^T (+epilogue) ----------------
// A: M x K bf16 row-major; B: N x K bf16 row-major. M%256==0, N%256==0, K%32==0,
// grid divisible by 8, K/32 >= 4.
// EPI 0: bf16 (acc+bias); EPI 1: bf16 silu(g)*(acc+bias); EPI 2: fp32 (acc+bias)
template<int EPI>
__global__ __launch_bounds__(512, 2)
void gemm256(const unsigned short* __restrict__ A,
             const unsigned short* __restrict__ B,
             const float* __restrict__ bias,
             const unsigned short* __restrict__ gbuf,
             void* __restrict__ Cv,
             int M, int N, int K) {
    __shared__ unsigned short lds[4 * 16384];   // 128 KiB, 4 K-tile ring

    const int tid  = threadIdx.x;
    const int lane = tid & 63;
    const int w    = tid >> 6;       // wave 0..7
    const int wm   = w >> 2;         // 0..1  (M half)
    const int wn   = w & 3;          // 0..3  (N quarter)

    // XCD-aware bijective swizzle (grid % 8 == 0)
    const int ntn = N >> 8;
    const int chunk = gridDim.x >> 3;
    const int sw = (blockIdx.x & 7) * chunk + (blockIdx.x >> 3);
    const int bm = sw / ntn, bn = sw % ntn;

    // ---- staging source decode (inverse swizzle; LDS dest stays linear) ----
    size_t gOfs[2];
#pragma unroll
    for (int i = 0; i < 2; ++i) {
        int lp  = i * 512 + tid;
        int pr  = lp >> 2, ps = lp & 3;
        int row = pr ^ ((pr >> 2) & 1);      // logical row (involution)
        int s   = ps ^ (row & 3);            // logical 16B slot within row
        gOfs[i] = (size_t)row * K + s * 8;
    }
    const unsigned short* Ag = A + (size_t)(bm * 256) * K;
    const unsigned short* Bg = B + (size_t)(bn * 256) * K;

    // ---- ds_read fragment addresses (swizzled) ----
    const int ar  = lane & 15;
    const int kg  = lane >> 4;
    const int rsw = ar ^ ((ar >> 2) & 1);
    const int ssw = (kg ^ (ar & 3)) * 8;
    const int aoff = (wm * 128 + rsw) * 32 + ssw;          // + m*512
    const int boff = 8192 + (wn * 64 + rsw) * 32 + ssw;    // + n*512

    f32x4 acc[8][4];
#pragma unroll
    for (int m = 0; m < 8; ++m)
#pragma unroll
        for (int n = 0; n < 4; ++n)
            acc[m][n] = (f32x4){0.f, 0.f, 0.f, 0.f};

    const int NT = K >> 5;

    // ---- prologue: stage K-tiles 0,1,2 ----
#pragma unroll
    for (int tt = 0; tt < 3; ++tt) {
        unsigned short* dS = lds + tt * 16384 + w * 512;
        const unsigned short* sA = Ag + tt * 32;
        const unsigned short* sB = Bg + tt * 32;
        GLL(sA + gOfs[0], dS);
        GLL(sA + gOfs[1], dS + 4096);
        GLL(sB + gOfs[0], dS + 8192);
        GLL(sB + gOfs[1], dS + 12288);
    }
    asm volatile("s_waitcnt vmcnt(8)" ::: "memory");   // tile 0 landed (1,2 in flight)
    __builtin_amdgcn_s_barrier();

    // preload tile-0 fragments: B (all 4) + A m0,m1
    bf16x8 b_[4], a0, a1;
#pragma unroll
    for (int n = 0; n < 4; ++n) b_[n] = *(const bf16x8*)(lds + boff + n * 512);
    a0 = *(const bf16x8*)(lds + aoff);
    a1 = *(const bf16x8*)(lds + aoff + 512);

#define MFMA_ROW(mi, af) \
    { _Pragma("unroll") \
      for (int n = 0; n < 4; ++n) \
          acc[mi][n] = __builtin_amdgcn_mfma_f32_16x16x32_bf16(af, b_[n], acc[mi][n], 0, 0, 0); }

    // ---- main loop: 4 phases/K-tile, 1 barrier/K-tile, reg dbuf frags ----
    for (int t = 0; t < NT; ++t) {
        const unsigned short* bufc = lds + (t & 3) * 16384;
        const unsigned short* bufn = lds + ((t + 1) & 3) * 16384;
        const int ts = (t + 3 < NT) ? (t + 3) : (NT - 1);   // clamped tail re-stage
        unsigned short* dS = lds + ((t + 3) & 3) * 16384 + w * 512;
        const unsigned short* sA = Ag + ts * 32;
        const unsigned short* sB = Bg + ts * 32;

        bf16x8 n0, n1;
        // p0: read m2,m3 | stage A#0 | MFMA m0,m1
        n0 = *(const bf16x8*)(bufc + aoff + 2 * 512);
        n1 = *(const bf16x8*)(bufc + aoff + 3 * 512);
        GLL(sA + gOfs[0], dS);
        __builtin_amdgcn_s_setprio(1);
        MFMA_ROW(0, a0); MFMA_ROW(1, a1);
        __builtin_amdgcn_s_setprio(0);
        a0 = n0; a1 = n1;
        // p1: read m4,m5 | stage A#1 | MFMA m2,m3
        n0 = *(const bf16x8*)(bufc + aoff + 4 * 512);
        n1 = *(const bf16x8*)(bufc + aoff + 5 * 512);
        GLL(sA + gOfs[1], dS + 4096);
        __builtin_amdgcn_s_setprio(1);
        MFMA_ROW(2, a0); MFMA_ROW(3, a1);
        __builtin_amdgcn_s_setprio(0);
        a0 = n0; a1 = n1;
        // p2: read m6,m7 | stage B#0 | MFMA m4,m5
        n0 = *(const bf16x8*)(bufc + aoff + 6 * 512);
        n1 = *(const bf16x8*)(bufc + aoff + 7 * 512);
        GLL(sB + gOfs[0], dS + 8192);
        __builtin_amdgcn_s_setprio(1);
        MFMA_ROW(4, a0); MFMA_ROW(5, a1);
        __builtin_amdgcn_s_setprio(0);
        a0 = n0; a1 = n1;
        // stage B#1; drain own LDS reads; counted vmcnt; tile barrier
        GLL(sB + gOfs[1], dS + 12288);
        asm volatile("s_waitcnt lgkmcnt(0)" ::: "memory");   // all my ds_reads done pre-barrier
        asm volatile("s_waitcnt vmcnt(8)" ::: "memory");     // tile t+1 landed; t+2,t+3 in flight
        __builtin_amdgcn_s_barrier();
        // p3: read next-tile B + m0,m1 | MFMA m6,m7
        bf16x8 bN0, bN1, bN2, bN3, f0, f1;
        bN0 = *(const bf16x8*)(bufn + boff);
        bN1 = *(const bf16x8*)(bufn + boff + 512);
        bN2 = *(const bf16x8*)(bufn + boff + 1024);
        bN3 = *(const bf16x8*)(bufn + boff + 1536);
        f0  = *(const bf16x8*)(bufn + aoff);
        f1  = *(const bf16x8*)(bufn + aoff + 512);
        __builtin_amdgcn_s_setprio(1);
        MFMA_ROW(6, a0); MFMA_ROW(7, a1);
        __builtin_amdgcn_s_setprio(0);
        b_[0] = bN0; b_[1] = bN1; b_[2] = bN2; b_[3] = bN3;
        a0 = f0; a1 = f1;
    }
#undef MFMA_ROW

    // ---- epilogue: C/D layout col=lane&15, row=(lane>>4)*4+j  [m89-verified] ----
    const int row0 = bm * 256 + wm * 128 + (lane >> 4) * 4;
    const int col0 = bn * 256 + wn * 64 + (lane & 15);
#pragma unroll
    for (int n = 0; n < 4; ++n) {
        const int col = col0 + n * 16;
        const float bv = bias[col];
#pragma unroll
        for (int m = 0; m < 8; ++m) {
            const int rb = row0 + m * 16;
#pragma unroll
            for (int j = 0; j < 4; ++j) {
                const size_t idx = (size_t)(rb + j) * (size_t)N + col;
                float v = acc[m][n][j] + bv;
                if (EPI == 0) {
                    ((unsigned short*)Cv)[idx] = f2bf(v);
                } else if (EPI == 1) {
                    float g = bf2f(gbuf[idx]);
                    float s = g / (1.f + __expf(-g));   // silu(g)
                    ((unsigned short*)Cv)[idx] = f2bf(s * v);
                } else {
                    ((float*)Cv)[idx] = v;
                }
            }
        }
    }
}

// ---------------- launcher ----------------
extern "C" void kernel_launch(void* const* d_in, const int* in_sizes, int n_in,
                              void* d_out, int out_size, void* d_ws, size_t ws_size,
                              hipStream_t stream) {
    const float* x  = (const float*)d_in[0];   // (2,2048,4096)
    const float* wg = (const float*)d_in[1];   // (11008,4096)
    const float* bg = (const float*)d_in[2];
    const float* wu = (const float*)d_in[3];
    const float* bu = (const float*)d_in[4];
    const float* wd = (const float*)d_in[5];   // (4096,11008)
    const float* bd = (const float*)d_in[6];

    const size_t NX = (size_t)M_TOK * HID;     // 16,777,216
    const size_t NW = (size_t)INT_ * HID;      // 45,088,768 (== M_TOK*INT_)

    unsigned short* ws = (unsigned short*)d_ws;
    unsigned short* Xb = ws;                   // x bf16
    unsigned short* S1 = Xb + NX;              // Wg -> later t
    unsigned short* S2 = S1 + NW;              // g  -> later Wd
    unsigned short* S3 = S2 + NW;              // Wu
    // peak ws need: (NX + 3*NW)*2 = 304,087,040 bytes

    dim3 blk512(512);
    dim3 blk256(256);
    const int CG = 2048;

    cvt_f32_bf16<<<CG, blk256, 0, stream>>>(x,  Xb, (int)(NX / 4));
    cvt_f32_bf16<<<CG, blk256, 0, stream>>>(wg, S1, (int)(NW / 4));
    // gate: g = x @ Wg^T + bg  (bf16 -> S2)   grid 16*43=688 (688%8==0)
    gemm256<0><<<dim3(16 * 43), blk512, 0, stream>>>(Xb, S1, bg, (const unsigned short*)nullptr,
                                                     (void*)S2, M_TOK, INT_, HID);
    cvt_f32_bf16<<<CG, blk256, 0, stream>>>(wu, S3, (int)(NW / 4));
    // up + fuse: t = silu(g) * (x @ Wu^T + bu)  (bf16 -> S1, Wg dead)
    gemm256<1><<<dim3(16 * 43), blk512, 0, stream>>>(Xb, S3, bu, S2,
                                                     (void*)S1, M_TOK, INT_, HID);
    cvt_f32_bf16<<<CG, blk256, 0, stream>>>(wd, S2, (int)(NW / 4));
    // down: out = t @ Wd^T + bd  (fp32 -> d_out)  grid 16*16=256 (256%8==0)
    gemm256<2><<<dim3(16 * 16), blk512, 0, stream>>>(S1, S2, bd, (const unsigned short*)nullptr,
                                                     d_out, M_TOK, HID, INT_);
}